// Round 15
// baseline (177.698 us; speedup 1.0000x reference)
//
#include <hip/hip_runtime.h>
#include <hip/hip_bf16.h>

typedef __attribute__((ext_vector_type(8))) short short8;
typedef __attribute__((ext_vector_type(4))) float f32x4;

static const int BB = 2;
static const int LL = 512;
#define MIN_F32 (-3.4028234663852886e+38f)
// Masked gab sentinel: must stay FINITE in bf16 (bf16(-FLT_MAX) -> -inf -> nan diff)
#define NEG_BIG (-1.0e38f)
#define SCALING_F 0.08838834764831845f
#define SQ2PI 2.5066282746310002f

// raw v_exp_f32: 2^x
__device__ __forceinline__ float exp2_hw(float x) {
    float r; asm("v_exp_f32 %0, %1" : "=v"(r) : "v"(x)); return r;
}
// Fast exact-gelu (A&S erf) -- used only to build the LUT (384 evals/block)
__device__ __forceinline__ float gelu_fast(float x) {
    float s  = x * 0.70710678118654752440f;
    float za = fabsf(s);
    float t  = __builtin_amdgcn_rcpf(fmaf(za, 0.3275911f, 1.0f));
    float p  = t * fmaf(t, fmaf(t, fmaf(t, fmaf(t, 1.061405429f, -1.453152027f),
                                        1.421413741f), -0.284496736f), 0.254829592f);
    float e  = __expf(-za * za);
    float q  = fmaf(-p, e, 1.0f);
    union { float f; unsigned u; } uq, us;
    uq.f = q; us.f = s;
    uq.u = (uq.u & 0x7FFFFFFFu) | (us.u & 0x80000000u);
    float hx = 0.5f * x;
    return fmaf(hx, uq.f, hx);
}
// packed bf16x2 via v_cvt_pk_bf16_f32 (RNE); lo -> low 16 bits
__device__ __forceinline__ unsigned pack_bf16x2(float lo, float hi) {
    __hip_bfloat162 h2 = __float22bfloat162_rn(float2{lo, hi});
    union { __hip_bfloat162 h; unsigned u; } v; v.h = h2;
    return v.u;
}
// Row-swizzled LDS byte offset for [row][128 bf16] tiles (row stride 256B).
__device__ __forceinline__ int swz(int row, int bytecol) {
    return row * 256 + (bytecol ^ ((row & 7) << 4));
}

// ---------------- main fused row kernel: one block per (b,i), 8 waves ----------------
// R8 lockstep phase structure (required: R9-R11 showed drifted gab stores amplify HBM
// traffic 4-5x). R15: W1/W2 MFMA fragments are tile-invariant per wave -> hoisted to
// registers once (LDS 81.4K->40K, P2/P3 LDS reads halved); GEMM2 operand-swapped so
// D[j][n] -> gab store is one dwordx4; ef-gen in quadratic exp2 form.
__global__ __launch_bounds__(512, 4) void row_kernel(
    const float* __restrict__ pos,
    const int*   __restrict__ nte,
    const unsigned char* __restrict__ adj,
    const unsigned char* __restrict__ padm,
    const unsigned char* __restrict__ molm,
    const unsigned char* __restrict__ clnm,
    const float* __restrict__ gmean,
    const float* __restrict__ gstd,
    const float* __restrict__ gmul,
    const float* __restrict__ gbias,
    const float* __restrict__ w1,
    const float* __restrict__ b1,
    const float* __restrict__ w2,
    const float* __restrict__ b2,
    const float* __restrict__ pw,
    const float* __restrict__ wfe,
    const float* __restrict__ wp,
    float* __restrict__ out_gab,
    float* __restrict__ pfe1,
    float* __restrict__ efsum,
    float* __restrict__ wfet,
    float* __restrict__ wpt)
{
    const int t = threadIdx.x;

    // ---- tail blocks: weight transpose for pfe_kernel ----
    if (blockIdx.x >= 1024) {
        int bid = blockIdx.x - 1024;          // 0..127
        #pragma unroll
        for (int q = 0; q < 4; ++q) {
            int idx = bid * 2048 + q * 512 + t;   // 0..262143
            int which = idx >> 17;
            int r = idx & 131071;                  // k*1024 + d
            int k = r >> 10;
            int d = r & 1023;
            if (which == 0) wfet[r] = wfe[d * 128 + k];
            else            wpt[r]  = wp[d * 128 + k];
        }
        return;
    }

    __shared__ __align__(16) char efs[64 * 256];   // bf16 [j=64][k=128], swizzled; scratch at end
    __shared__ __align__(16) char hs [64 * 256];   // bf16 [j=64][jo=128], swizzled
    __shared__ float dist_row[512];
    __shared__ float xval[512];
    __shared__ __align__(4) unsigned char flgall[512];
    __shared__ float b1s[128];
    __shared__ float b2s[32];
    __shared__ float sred[16];
    __shared__ float dsump[128];
    __shared__ float gelu_tab[384];   // gelu on [-6,6], step 1/32

    const int row = blockIdx.x;     // b*512 + i
    const int b = row >> 9;
    const int i = row & 511;

    const int w  = t >> 6;          // wave 0..7
    const int l  = t & 63;          // lane
    const int lr = l & 15;          // frag row/col index
    const int lq = l >> 4;          // frag k-group

    const int jobase = (w & 3) * 32;   // GEMM1: 2 jo-tiles per wave (tile-invariant)
    const int jbase  = (w >> 2) * 32;  // GEMM1: 2 j-tiles per wave
    const int mt  = w >> 2;            // GEMM2: n-half (tile-invariant)
    const int jt2 = w & 3;             // GEMM2: j-tile

    if (t < 128) b1s[t] = b1[t];
    if (t < 32)  b2s[t] = b2[t];
    if (t < 384) gelu_tab[t] = gelu_fast((t - 192) * 0.03125f);

    // ---- W1/W2 MFMA fragments: global -> registers ONCE (jo/mt fixed per wave) ----
    short8 w1f0[4], w1f1[4], w2f[4];
    {
        const float* r0p = w1 + (jobase + lr) * 128;
        const float* r1p = w1 + (jobase + 16 + lr) * 128;
        const float* r2p = w2 + (mt * 16 + lr) * 128;
        #pragma unroll
        for (int ks = 0; ks < 4; ++ks) {
            int off = ks * 32 + lq * 8;
            union { uint4 u; short8 s; } cv;
            float4 x0 = *(const float4*)(r0p + off), x1 = *(const float4*)(r0p + off + 4);
            cv.u = make_uint4(pack_bf16x2(x0.x, x0.y), pack_bf16x2(x0.z, x0.w),
                              pack_bf16x2(x1.x, x1.y), pack_bf16x2(x1.z, x1.w));
            w1f0[ks] = cv.s;
            float4 y0 = *(const float4*)(r1p + off), y1 = *(const float4*)(r1p + off + 4);
            cv.u = make_uint4(pack_bf16x2(y0.x, y0.y), pack_bf16x2(y0.z, y0.w),
                              pack_bf16x2(y1.x, y1.y), pack_bf16x2(y1.z, y1.w));
            w1f1[ks] = cv.s;
            float4 z0 = *(const float4*)(r2p + off), z1 = *(const float4*)(r2p + off + 4);
            cv.u = make_uint4(pack_bf16x2(z0.x, z0.y), pack_bf16x2(z0.z, z0.w),
                              pack_bf16x2(z1.x, z1.y), pack_bf16x2(z1.z, z1.w));
            w2f[ks] = cv.s;
        }
    }

    const bool pad_i = padm[row] != 0;
    const bool force_adj = (clnm[row] != 0) || (molm[row] == 0);
    const float pix = pos[row * 3 + 0], piy = pos[row * 3 + 1], piz = pos[row * 3 + 2];

    // ---- per-j scalars for ALL 512 j, fully parallel (1 j / thread) ----
    {
        int2 e2 = ((const int2*)nte)[row * 512 + t];
        float mul = gmul[e2.x] + gmul[e2.y];
        float bia = gbias[e2.x] + gbias[e2.y];
        float dx = pix - pos[(b * 512 + t) * 3 + 0];
        float dy = piy - pos[(b * 512 + t) * 3 + 1];
        float dz = piz - pos[(b * 512 + t) * 3 + 2];
        float dist = sqrtf(dx * dx + dy * dy + dz * dz + 1e-12f);
        xval[t] = mul * dist + bia;
        int padj = padm[b * 512 + t] ? 1 : 0;
        int adje = (force_adj || adj[row * 512 + t]) ? 2 : 0;
        flgall[t] = (unsigned char)(padj | adje);
    }

    // ---- gaussian params, quadratic exp2 form: e = 2^(Aq x^2 + Bq x + Cq) ----
    const int k0 = (t & 15) * 8;
    const int js = t >> 4;          // j-slot 0..31
    float Aq[8], Bq[8], Cq[8], efacc[8];
    #pragma unroll
    for (int q = 0; q < 8; ++q) {
        float gsv = fabsf(gstd[k0 + q]) + 1e-5f;
        float mn  = gmean[k0 + q];
        float is  = 0.84932180f / gsv;      // sqrt(0.5*log2(e))/sigma
        float s   = is * is;
        Aq[q] = -s;
        Bq[q] = 2.0f * mn * s;
        Cq[q] = -log2f(SQ2PI * gsv) - mn * mn * s;
        efacc[q] = 0.f;
    }

    // gelu via LUT (R14-proven): clamp -> interp; exactness only needed to bf16
    auto gelu_lut = [&](float x) -> float {
        float xc = fminf(fmaxf(x, -6.0f), 6.0f);
        float f  = fminf(fmaf(xc, 32.0f, 192.0f), 382.99f);
        float ff = floorf(f);
        float fr = f - ff;
        int idx = (int)ff;
        float v0 = gelu_tab[idx];
        float v1 = gelu_tab[idx + 1];
        float r = fmaf(fr, v1 - v0, v0);
        return x > 5.9f ? x : r;
    };

    __syncthreads();

    for (int tile = 0; tile < 8; ++tile) {
        const int j0 = tile * 64;
        // P1: ef-gen (+ previous tile's dist combine rides here)
        if (tile > 0 && t < 64) {
            int fl = flgall[j0 - 64 + t];
            bool masked = pad_i || (fl & 1) || !(fl & 2);
            dist_row[j0 - 64 + t] = masked ? MIN_F32 : (dsump[t] + dsump[64 + t]);
        }
        #pragma unroll
        for (int jj = 0; jj < 2; ++jj) {
            int j = js + jj * 32;
            float x  = xval[j0 + j];
            float mk = (flgall[j0 + j] & 1) ? 0.0f : 1.0f;
            unsigned pk[4];
            #pragma unroll
            for (int q = 0; q < 4; ++q) {
                float e0 = exp2_hw(fmaf(x, fmaf(x, Aq[2*q+0], Bq[2*q+0]), Cq[2*q+0]));
                float e1 = exp2_hw(fmaf(x, fmaf(x, Aq[2*q+1], Bq[2*q+1]), Cq[2*q+1]));
                efacc[2*q+0] = fmaf(e0, mk, efacc[2*q+0]);
                efacc[2*q+1] = fmaf(e1, mk, efacc[2*q+1]);
                pk[q] = pack_bf16x2(e0, e1);
            }
            *(uint4*)(efs + swz(j, 2 * k0)) = make_uint4(pk[0], pk[1], pk[2], pk[3]);
        }
        __syncthreads();
        // P2: GEMM1  D[jo][j] = W1 @ ef^T (W1 frags in regs), gelu-LUT -> hs[j][jo]
        {
            f32x4 a00 = {0.f,0.f,0.f,0.f}, a01 = a00, a10 = a00, a11 = a00;
            #pragma unroll
            for (int ks = 0; ks < 4; ++ks) {
                int bcol = ks * 64 + lq * 16;
                short8 bv0 = *(const short8*)(efs + swz(jbase + lr, bcol));
                short8 bv1 = *(const short8*)(efs + swz(jbase + 16 + lr, bcol));
                a00 = __builtin_amdgcn_mfma_f32_16x16x32_bf16(w1f0[ks], bv0, a00, 0, 0, 0);
                a01 = __builtin_amdgcn_mfma_f32_16x16x32_bf16(w1f0[ks], bv1, a01, 0, 0, 0);
                a10 = __builtin_amdgcn_mfma_f32_16x16x32_bf16(w1f1[ks], bv0, a10, 0, 0, 0);
                a11 = __builtin_amdgcn_mfma_f32_16x16x32_bf16(w1f1[ks], bv1, a11, 0, 0, 0);
            }
            #pragma unroll
            for (int mi = 0; mi < 2; ++mi) {
                int jo0 = jobase + mi * 16 + lq * 4;
                float4 bb = *(const float4*)&b1s[jo0];
                #pragma unroll
                for (int ci = 0; ci < 2; ++ci) {
                    f32x4 acc = (mi == 0) ? (ci == 0 ? a00 : a01) : (ci == 0 ? a10 : a11);
                    int j = jbase + ci * 16 + lr;
                    float g0 = gelu_lut(acc[0] + bb.x);
                    float g1 = gelu_lut(acc[1] + bb.y);
                    float g2 = gelu_lut(acc[2] + bb.z);
                    float g3 = gelu_lut(acc[3] + bb.w);
                    uint2 pv = make_uint2(pack_bf16x2(g0, g1), pack_bf16x2(g2, g3));
                    *(uint2*)(hs + swz(j, 2 * jo0)) = pv;
                }
            }
        }
        __syncthreads();
        // P3: GEMM2 swapped  D[j][n] = h @ W2^T (W2 frags in regs) -> dwordx4 gab store
        {
            f32x4 acc = (f32x4){0.f, 0.f, 0.f, 0.f};
            #pragma unroll
            for (int ks = 0; ks < 4; ++ks) {
                short8 af = *(const short8*)(hs + swz(jt2 * 16 + lr, ks * 64 + lq * 16));
                acc = __builtin_amdgcn_mfma_f32_16x16x32_bf16(af, w2f[ks], acc, 0, 0, 0);
            }
            int n  = mt * 16 + lr;
            int jl = jt2 * 16 + lq * 4;        // first of 4 consecutive j (local)
            int jq = j0 + jl;
            float bb = b2s[n];
            f32x4 raw;
            #pragma unroll
            for (int r = 0; r < 4; ++r) raw[r] = acc[r] + bb;
            // dist: reduce raw over the 16 n-lanes (masks 1,2,4,8 stay in-group)
            f32x4 red = raw;
            #pragma unroll
            for (int m = 1; m <= 8; m <<= 1) {
                #pragma unroll
                for (int r = 0; r < 4; ++r) red[r] += __shfl_xor(red[r], m);
            }
            if (lr == 0)
                *(float4*)&dsump[mt * 64 + jl] = make_float4(red[0], red[1], red[2], red[3]);
            unsigned fl4 = *(const unsigned*)&flgall[jq];
            f32x4 ov;
            #pragma unroll
            for (int r = 0; r < 4; ++r) {
                int fl = (fl4 >> (8 * r)) & 255;
                bool kill = (fl & 1) || !(fl & 2);
                ov[r] = pad_i ? 0.0f : (kill ? NEG_BIG : raw[r]);
            }
            *(f32x4*)&out_gab[((size_t)(b * 32 + n) * 512 + i) * 512 + jq] = ov;
        }
        __syncthreads();
    }

    // last tile's dist combine + efsum flush (efs free -> scratch)
    float* rb = (float*)efs;
    if (t < 64) {
        int fl = flgall[448 + t];
        bool masked = pad_i || (fl & 1) || !(fl & 2);
        dist_row[448 + t] = masked ? MIN_F32 : (dsump[t] + dsump[64 + t]);
    }
    *(float4*)&rb[t * 8 + 0] = make_float4(efacc[0], efacc[1], efacc[2], efacc[3]);
    *(float4*)&rb[t * 8 + 4] = make_float4(efacc[4], efacc[5], efacc[6], efacc[7]);
    __syncthreads();
    if (t < 128) {
        float s = 0.f;
        #pragma unroll
        for (int sidx = 0; sidx < 32; ++sidx) s += rb[sidx * 128 + t];
        efsum[(size_t)row * 128 + t] = s;
    }

    // ---- softmax over dist_row ----
    float sv = dist_row[t] * SCALING_F;
    float v = sv;
    #pragma unroll
    for (int m = 32; m > 0; m >>= 1) v = fmaxf(v, __shfl_xor(v, m));
    if ((t & 63) == 0) sred[t >> 6] = v;
    __syncthreads();
    float mx = sred[0];
    #pragma unroll
    for (int w8 = 1; w8 < 8; ++w8) mx = fmaxf(mx, sred[w8]);
    float e = expf(sv - mx);
    v = e;
    #pragma unroll
    for (int m = 32; m > 0; m >>= 1) v += __shfl_xor(v, m);
    if ((t & 63) == 0) sred[8 + (t >> 6)] = v;
    __syncthreads();
    float sm = 0.f;
    #pragma unroll
    for (int w8 = 0; w8 < 8; ++w8) sm += sred[8 + w8];
    float p = e / sm;

    // ---- pfe1 via linearity: pfe1[k] = pw[k] . (sum_j p[j]*pos[j]) ----
    float px = pos[(b * 512 + t) * 3 + 0];
    float py = pos[(b * 512 + t) * 3 + 1];
    float pz = pos[(b * 512 + t) * 3 + 2];
    float vx = p * px, vy = p * py, vz = p * pz;
    #pragma unroll
    for (int m = 32; m > 0; m >>= 1) {
        vx += __shfl_xor(vx, m); vy += __shfl_xor(vy, m); vz += __shfl_xor(vz, m);
    }
    __syncthreads();      // rb re-use after efsum reads done
    if ((t & 63) == 0) {
        int w8 = t >> 6;
        rb[w8] = vx; rb[8 + w8] = vy; rb[16 + w8] = vz;
    }
    __syncthreads();
    if (t < 128) {
        float w0 = 0.f, w1v = 0.f, w2v = 0.f;
        #pragma unroll
        for (int w8 = 0; w8 < 8; ++w8) {
            w0 += rb[w8]; w1v += rb[8 + w8]; w2v += rb[16 + w8];
        }
        pfe1[(size_t)row * 128 + t] = pw[t * 3 + 0] * w0 + pw[t * 3 + 1] * w1v + pw[t * 3 + 2] * w2v;
    }
}

// ---------------- final projection: tiled f32 GEMM ----------------
__global__ __launch_bounds__(256) void pfe_kernel(
    const float* __restrict__ pfe1,
    const float* __restrict__ efsum,
    const float* __restrict__ wfet,   // [K=128][D=1024]
    const float* __restrict__ wpt,    // [K=128][D=1024]
    const float* __restrict__ pb,
    const unsigned char* __restrict__ padm,
    float* __restrict__ out)
{
    __shared__ __align__(16) float As[2 * 32 * 132];
    __shared__ __align__(16) float Bs[2 * 16 * 128];
    const int t  = threadIdx.x;
    const int tx = t & 31;
    const int ty = t >> 5;
    const int r0 = (blockIdx.x >> 3) * 32;
    const int d0 = (blockIdx.x & 7) * 128;

    #pragma unroll
    for (int q = 0; q < 16; ++q) {
        int ii = t + q * 256;
        int r = ii >> 7, k = ii & 127;
        As[(0 * 32 + r) * 132 + k] = pfe1 [(size_t)(r0 + r) * 128 + k];
        As[(1 * 32 + r) * 132 + k] = efsum[(size_t)(r0 + r) * 128 + k];
    }

    f32x4 acc[4];
    #pragma unroll
    for (int rr = 0; rr < 4; ++rr) acc[rr] = (f32x4){0.f, 0.f, 0.f, 0.f};

    for (int kc = 0; kc < 8; ++kc) {
        __syncthreads();
        #pragma unroll
        for (int q = 0; q < 2; ++q) {
            int ii = t + q * 256;
            int kr = ii >> 5, dq = ii & 31;
            f32x4 v0 = ((const f32x4*)(wfet + (size_t)(kc * 16 + kr) * 1024 + d0))[dq];
            f32x4 v1 = ((const f32x4*)(wpt  + (size_t)(kc * 16 + kr) * 1024 + d0))[dq];
            *(f32x4*)&Bs[(0 * 16 + kr) * 128 + dq * 4] = v0;
            *(f32x4*)&Bs[(1 * 16 + kr) * 128 + dq * 4] = v1;
        }
        __syncthreads();
        #pragma unroll
        for (int k4 = 0; k4 < 4; ++k4) {
            int kb = kc * 16 + k4 * 4;
            f32x4 a0[4], a1[4];
            #pragma unroll
            for (int rr = 0; rr < 4; ++rr) {
                int r = ty * 4 + rr;
                a0[rr] = *(const f32x4*)&As[(0 * 32 + r) * 132 + kb];
                a1[rr] = *(const f32x4*)&As[(1 * 32 + r) * 132 + kb];
            }
            #pragma unroll
            for (int kq = 0; kq < 4; ++kq) {
                f32x4 b0 = *(const f32x4*)&Bs[(0 * 16 + k4 * 4 + kq) * 128 + tx * 4];
                f32x4 b1 = *(const f32x4*)&Bs[(1 * 16 + k4 * 4 + kq) * 128 + tx * 4];
                #pragma unroll
                for (int rr = 0; rr < 4; ++rr) {
                    acc[rr] += a0[rr][kq] * b0 + a1[rr][kq] * b1;
                }
            }
        }
    }

    f32x4 bv = *(const f32x4*)&pb[d0 + tx * 4];
    #pragma unroll
    for (int rr = 0; rr < 4; ++rr) {
        int row = r0 + ty * 4 + rr;
        f32x4 o = acc[rr] + bv;
        if (padm[row]) o = (f32x4){0.f, 0.f, 0.f, 0.f};
        *(f32x4*)&out[(size_t)row * 1024 + d0 + tx * 4] = o;
    }
}

extern "C" void kernel_launch(void* const* d_in, const int* in_sizes, int n_in,
                              void* d_out, int out_size, void* d_ws, size_t ws_size,
                              hipStream_t stream) {
    const float* pos  = (const float*)d_in[0];
    const int*   nte  = (const int*)d_in[1];
    const unsigned char* adj  = (const unsigned char*)d_in[2];
    const unsigned char* padm = (const unsigned char*)d_in[3];
    const unsigned char* molm = (const unsigned char*)d_in[4];
    const unsigned char* clnm = (const unsigned char*)d_in[5];
    const float* pw    = (const float*)d_in[6];
    const float* wfe   = (const float*)d_in[7];
    const float* gmean = (const float*)d_in[8];
    const float* gstd  = (const float*)d_in[9];
    const float* gmul  = (const float*)d_in[10];
    const float* gbias = (const float*)d_in[11];
    const float* w1    = (const float*)d_in[12];
    const float* b1    = (const float*)d_in[13];
    const float* w2    = (const float*)d_in[14];
    const float* b2    = (const float*)d_in[15];
    const float* wp    = (const float*)d_in[16];
    const float* pb    = (const float*)d_in[17];

    float* out      = (float*)d_out;
    float* out_pfe  = out;
    float* out_gab  = out + (size_t)BB * LL * 1024;

    float* ws    = (float*)d_ws;
    float* pfe1  = ws;                  // 131072
    float* efsum = ws + 131072;         // 131072
    float* wfet  = ws + 262144;         // 131072
    float* wpt   = ws + 393216;         // 131072

    row_kernel<<<BB * LL + 128, 512, 0, stream>>>(pos, nte, adj, padm, molm, clnm,
                                                  gmean, gstd, gmul, gbias,
                                                  w1, b1, w2, b2, pw, wfe, wp,
                                                  out_gab, pfe1, efsum, wfet, wpt);
    pfe_kernel<<<256, 256, 0, stream>>>(pfe1, efsum, wfet, wpt, pb, padm, out_pfe);
}

// Round 16
// 128.090 us; speedup vs baseline: 1.3873x; 1.3873x over previous
//
#include <hip/hip_runtime.h>
#include <hip/hip_bf16.h>

typedef __attribute__((ext_vector_type(8))) short short8;
typedef __attribute__((ext_vector_type(4))) float f32x4;

static const int BB = 2;
static const int LL = 512;
#define MIN_F32 (-3.4028234663852886e+38f)
// Masked gab sentinel: must stay FINITE in bf16 (bf16(-FLT_MAX) -> -inf -> nan diff)
#define NEG_BIG (-1.0e38f)
#define SCALING_F 0.08838834764831845f
#define SQ2PI 2.5066282746310002f

// raw v_exp_f32: 2^x
__device__ __forceinline__ float exp2_hw(float x) {
    float r; asm("v_exp_f32 %0, %1" : "=v"(r) : "v"(x)); return r;
}
// Fast exact-gelu (A&S erf) -- used only to build the LUT (384 evals/block)
__device__ __forceinline__ float gelu_fast(float x) {
    float s  = x * 0.70710678118654752440f;
    float za = fabsf(s);
    float t  = __builtin_amdgcn_rcpf(fmaf(za, 0.3275911f, 1.0f));
    float p  = t * fmaf(t, fmaf(t, fmaf(t, fmaf(t, 1.061405429f, -1.453152027f),
                                        1.421413741f), -0.284496736f), 0.254829592f);
    float e  = __expf(-za * za);
    float q  = fmaf(-p, e, 1.0f);
    union { float f; unsigned u; } uq, us;
    uq.f = q; us.f = s;
    uq.u = (uq.u & 0x7FFFFFFFu) | (us.u & 0x80000000u);
    float hx = 0.5f * x;
    return fmaf(hx, uq.f, hx);
}
// packed bf16x2 via v_cvt_pk_bf16_f32 (RNE); lo -> low 16 bits
__device__ __forceinline__ unsigned pack_bf16x2(float lo, float hi) {
    __hip_bfloat162 h2 = __float22bfloat162_rn(float2{lo, hi});
    union { __hip_bfloat162 h; unsigned u; } v; v.h = h2;
    return v.u;
}
// f2bf scalar (weight staging only, once per block)
__device__ __forceinline__ unsigned short f2bf(float f) {
    union { float f; unsigned int u; } v; v.f = f;
    unsigned int u = v.u;
    return (unsigned short)((u + 0x7FFFu + ((u >> 16) & 1u)) >> 16);
}
// Row-swizzled LDS byte offset for [row][128 bf16] tiles (row stride 256B).
__device__ __forceinline__ int swz(int row, int bytecol) {
    return row * 256 + (bytecol ^ ((row & 7) << 4));
}

// ---------------- main fused row kernel: one block per (b,i), 8 waves ----------------
// R8 lockstep phase structure (R9-R11: drifted gab stores amplify HBM 4-5x).
// R15 lesson: hoisting W1+W2 frags (48 VGPR) spilled to scratch (WRITE 200MB) --
// launch_bounds(512,4) caps the allocator. R16: hoist ONLY W2 (16 VGPR), W1 stays
// in LDS; GEMM2 swapped -> D[j][n], gab store = one dwordx4; quadratic exp2 ef-gen.
__global__ __launch_bounds__(512, 4) void row_kernel(
    const float* __restrict__ pos,
    const int*   __restrict__ nte,
    const unsigned char* __restrict__ adj,
    const unsigned char* __restrict__ padm,
    const unsigned char* __restrict__ molm,
    const unsigned char* __restrict__ clnm,
    const float* __restrict__ gmean,
    const float* __restrict__ gstd,
    const float* __restrict__ gmul,
    const float* __restrict__ gbias,
    const float* __restrict__ w1,
    const float* __restrict__ b1,
    const float* __restrict__ w2,
    const float* __restrict__ b2,
    const float* __restrict__ pw,
    const float* __restrict__ wfe,
    const float* __restrict__ wp,
    float* __restrict__ out_gab,
    float* __restrict__ pfe1,
    float* __restrict__ efsum,
    float* __restrict__ wfet,
    float* __restrict__ wpt)
{
    const int t = threadIdx.x;

    // ---- tail blocks: weight transpose for pfe_kernel ----
    if (blockIdx.x >= 1024) {
        int bid = blockIdx.x - 1024;          // 0..127
        #pragma unroll
        for (int q = 0; q < 4; ++q) {
            int idx = bid * 2048 + q * 512 + t;   // 0..262143
            int which = idx >> 17;
            int r = idx & 131071;                  // k*1024 + d
            int k = r >> 10;
            int d = r & 1023;
            if (which == 0) wfet[r] = wfe[d * 128 + k];
            else            wpt[r]  = wp[d * 128 + k];
        }
        return;
    }

    __shared__ __align__(16) char W1s[128 * 256];  // bf16 [jo=128][k=128], swizzled
    __shared__ __align__(16) char efs[64 * 256];   // bf16 [j=64][k=128], swizzled; scratch at end
    __shared__ __align__(16) char hs [64 * 256];   // bf16 [j=64][jo=128], swizzled
    __shared__ float dist_row[512];
    __shared__ float xval[512];
    __shared__ __align__(4) unsigned char flgall[512];
    __shared__ float b1s[128];
    __shared__ float b2s[32];
    __shared__ float sred[16];
    __shared__ float dsump[128];
    __shared__ float gelu_tab[384];   // gelu on [-6,6], step 1/32

    const int row = blockIdx.x;     // b*512 + i
    const int b = row >> 9;
    const int i = row & 511;

    const int w  = t >> 6;          // wave 0..7
    const int l  = t & 63;          // lane
    const int lr = l & 15;          // frag row/col index
    const int lq = l >> 4;          // frag k-group

    const int jobase = (w & 3) * 32;   // GEMM1: 2 jo-tiles per wave
    const int jbase  = (w >> 2) * 32;  // GEMM1: 2 j-tiles per wave
    const int mt  = w >> 2;            // GEMM2: n-half
    const int jt2 = w & 3;             // GEMM2: j-tile

    // ---- stage W1 as bf16, swizzled (LDS; R15 showed hoisting it spills) ----
    for (int idx = t; idx < 2048; idx += 512) {
        int r16 = idx >> 4, c16 = idx & 15;
        const float* src = w1 + r16 * 128 + c16 * 8;
        float4 f0 = *(const float4*)(src);
        float4 f1 = *(const float4*)(src + 4);
        uint4 pk;
        pk.x = (unsigned)f2bf(f0.x) | ((unsigned)f2bf(f0.y) << 16);
        pk.y = (unsigned)f2bf(f0.z) | ((unsigned)f2bf(f0.w) << 16);
        pk.z = (unsigned)f2bf(f1.x) | ((unsigned)f2bf(f1.y) << 16);
        pk.w = (unsigned)f2bf(f1.z) | ((unsigned)f2bf(f1.w) << 16);
        *(uint4*)(W1s + swz(r16, c16 * 16)) = pk;
    }
    if (t < 128) b1s[t] = b1[t];
    if (t < 32)  b2s[t] = b2[t];
    if (t < 384) gelu_tab[t] = gelu_fast((t - 192) * 0.03125f);

    // ---- W2 fragments only: global -> registers (16 VGPR, fits under cap) ----
    short8 w2f[4];
    {
        const float* r2p = w2 + (mt * 16 + lr) * 128;
        #pragma unroll
        for (int ks = 0; ks < 4; ++ks) {
            int off = ks * 32 + lq * 8;
            union { uint4 u; short8 s; } cv;
            float4 z0 = *(const float4*)(r2p + off), z1 = *(const float4*)(r2p + off + 4);
            cv.u = make_uint4(pack_bf16x2(z0.x, z0.y), pack_bf16x2(z0.z, z0.w),
                              pack_bf16x2(z1.x, z1.y), pack_bf16x2(z1.z, z1.w));
            w2f[ks] = cv.s;
        }
    }

    const bool pad_i = padm[row] != 0;
    const bool force_adj = (clnm[row] != 0) || (molm[row] == 0);
    const float pix = pos[row * 3 + 0], piy = pos[row * 3 + 1], piz = pos[row * 3 + 2];

    // ---- per-j scalars for ALL 512 j, fully parallel (1 j / thread) ----
    {
        int2 e2 = ((const int2*)nte)[row * 512 + t];
        float mul = gmul[e2.x] + gmul[e2.y];
        float bia = gbias[e2.x] + gbias[e2.y];
        float dx = pix - pos[(b * 512 + t) * 3 + 0];
        float dy = piy - pos[(b * 512 + t) * 3 + 1];
        float dz = piz - pos[(b * 512 + t) * 3 + 2];
        float dist = sqrtf(dx * dx + dy * dy + dz * dz + 1e-12f);
        xval[t] = mul * dist + bia;
        int padj = padm[b * 512 + t] ? 1 : 0;
        int adje = (force_adj || adj[row * 512 + t]) ? 2 : 0;
        flgall[t] = (unsigned char)(padj | adje);
    }

    // ---- gaussian params, quadratic exp2 form: e = 2^(Aq x^2 + Bq x + Cq) ----
    const int k0 = (t & 15) * 8;
    const int js = t >> 4;          // j-slot 0..31
    float Aq[8], Bq[8], Cq[8], efacc[8];
    #pragma unroll
    for (int q = 0; q < 8; ++q) {
        float gsv = fabsf(gstd[k0 + q]) + 1e-5f;
        float mn  = gmean[k0 + q];
        float is  = 0.84932180f / gsv;      // sqrt(0.5*log2(e))/sigma
        float s   = is * is;
        Aq[q] = -s;
        Bq[q] = 2.0f * mn * s;
        Cq[q] = -log2f(SQ2PI * gsv) - mn * mn * s;
        efacc[q] = 0.f;
    }

    // gelu via LUT (R14-proven)
    auto gelu_lut = [&](float x) -> float {
        float xc = fminf(fmaxf(x, -6.0f), 6.0f);
        float f  = fminf(fmaf(xc, 32.0f, 192.0f), 382.99f);
        float ff = floorf(f);
        float fr = f - ff;
        int idx = (int)ff;
        float v0 = gelu_tab[idx];
        float v1 = gelu_tab[idx + 1];
        float r = fmaf(fr, v1 - v0, v0);
        return x > 5.9f ? x : r;
    };

    __syncthreads();

    for (int tile = 0; tile < 8; ++tile) {
        const int j0 = tile * 64;
        // P1: ef-gen (+ previous tile's dist combine rides here)
        if (tile > 0 && t < 64) {
            int fl = flgall[j0 - 64 + t];
            bool masked = pad_i || (fl & 1) || !(fl & 2);
            dist_row[j0 - 64 + t] = masked ? MIN_F32 : (dsump[t] + dsump[64 + t]);
        }
        #pragma unroll
        for (int jj = 0; jj < 2; ++jj) {
            int j = js + jj * 32;
            float x  = xval[j0 + j];
            float mk = (flgall[j0 + j] & 1) ? 0.0f : 1.0f;
            unsigned pk[4];
            #pragma unroll
            for (int q = 0; q < 4; ++q) {
                float e0 = exp2_hw(fmaf(x, fmaf(x, Aq[2*q+0], Bq[2*q+0]), Cq[2*q+0]));
                float e1 = exp2_hw(fmaf(x, fmaf(x, Aq[2*q+1], Bq[2*q+1]), Cq[2*q+1]));
                efacc[2*q+0] = fmaf(e0, mk, efacc[2*q+0]);
                efacc[2*q+1] = fmaf(e1, mk, efacc[2*q+1]);
                pk[q] = pack_bf16x2(e0, e1);
            }
            *(uint4*)(efs + swz(j, 2 * k0)) = make_uint4(pk[0], pk[1], pk[2], pk[3]);
        }
        __syncthreads();
        // P2: GEMM1 swapped  D[jo][j] = W1 @ ef^T (W1 from LDS), gelu-LUT -> hs[j][jo]
        {
            f32x4 a00 = {0.f,0.f,0.f,0.f}, a01 = a00, a10 = a00, a11 = a00;
            #pragma unroll
            for (int ks = 0; ks < 4; ++ks) {
                int bcol = ks * 64 + lq * 16;
                short8 av0 = *(const short8*)(W1s + swz(jobase + lr, bcol));
                short8 av1 = *(const short8*)(W1s + swz(jobase + 16 + lr, bcol));
                short8 bv0 = *(const short8*)(efs + swz(jbase + lr, bcol));
                short8 bv1 = *(const short8*)(efs + swz(jbase + 16 + lr, bcol));
                a00 = __builtin_amdgcn_mfma_f32_16x16x32_bf16(av0, bv0, a00, 0, 0, 0);
                a01 = __builtin_amdgcn_mfma_f32_16x16x32_bf16(av0, bv1, a01, 0, 0, 0);
                a10 = __builtin_amdgcn_mfma_f32_16x16x32_bf16(av1, bv0, a10, 0, 0, 0);
                a11 = __builtin_amdgcn_mfma_f32_16x16x32_bf16(av1, bv1, a11, 0, 0, 0);
            }
            #pragma unroll
            for (int mi = 0; mi < 2; ++mi) {
                int jo0 = jobase + mi * 16 + lq * 4;
                float4 bb = *(const float4*)&b1s[jo0];
                #pragma unroll
                for (int ci = 0; ci < 2; ++ci) {
                    f32x4 acc = (mi == 0) ? (ci == 0 ? a00 : a01) : (ci == 0 ? a10 : a11);
                    int j = jbase + ci * 16 + lr;
                    float g0 = gelu_lut(acc[0] + bb.x);
                    float g1 = gelu_lut(acc[1] + bb.y);
                    float g2 = gelu_lut(acc[2] + bb.z);
                    float g3 = gelu_lut(acc[3] + bb.w);
                    uint2 pv = make_uint2(pack_bf16x2(g0, g1), pack_bf16x2(g2, g3));
                    *(uint2*)(hs + swz(j, 2 * jo0)) = pv;
                }
            }
        }
        __syncthreads();
        // P3: GEMM2 swapped  D[j][n] = h @ W2^T (W2 in regs) -> one dwordx4 gab store
        {
            f32x4 acc = (f32x4){0.f, 0.f, 0.f, 0.f};
            #pragma unroll
            for (int ks = 0; ks < 4; ++ks) {
                short8 af = *(const short8*)(hs + swz(jt2 * 16 + lr, ks * 64 + lq * 16));
                acc = __builtin_amdgcn_mfma_f32_16x16x32_bf16(af, w2f[ks], acc, 0, 0, 0);
            }
            int n  = mt * 16 + lr;
            int jl = jt2 * 16 + lq * 4;        // first of 4 consecutive j (local)
            int jq = j0 + jl;
            float bb = b2s[n];
            f32x4 raw;
            #pragma unroll
            for (int r = 0; r < 4; ++r) raw[r] = acc[r] + bb;
            // dist: reduce raw over the 16 n-lanes (masks 1,2,4,8 stay in lr-group)
            f32x4 red = raw;
            #pragma unroll
            for (int m = 1; m <= 8; m <<= 1) {
                #pragma unroll
                for (int r = 0; r < 4; ++r) red[r] += __shfl_xor(red[r], m);
            }
            if (lr == 0)
                *(float4*)&dsump[mt * 64 + jl] = make_float4(red[0], red[1], red[2], red[3]);
            unsigned fl4 = *(const unsigned*)&flgall[jq];
            f32x4 ov;
            #pragma unroll
            for (int r = 0; r < 4; ++r) {
                int fl = (fl4 >> (8 * r)) & 255;
                bool kill = (fl & 1) || !(fl & 2);
                ov[r] = pad_i ? 0.0f : (kill ? NEG_BIG : raw[r]);
            }
            *(f32x4*)&out_gab[((size_t)(b * 32 + n) * 512 + i) * 512 + jq] = ov;
        }
        __syncthreads();
    }

    // last tile's dist combine + efsum flush (efs free -> scratch)
    float* rb = (float*)efs;
    if (t < 64) {
        int fl = flgall[448 + t];
        bool masked = pad_i || (fl & 1) || !(fl & 2);
        dist_row[448 + t] = masked ? MIN_F32 : (dsump[t] + dsump[64 + t]);
    }
    *(float4*)&rb[t * 8 + 0] = make_float4(efacc[0], efacc[1], efacc[2], efacc[3]);
    *(float4*)&rb[t * 8 + 4] = make_float4(efacc[4], efacc[5], efacc[6], efacc[7]);
    __syncthreads();
    if (t < 128) {
        float s = 0.f;
        #pragma unroll
        for (int sidx = 0; sidx < 32; ++sidx) s += rb[sidx * 128 + t];
        efsum[(size_t)row * 128 + t] = s;
    }

    // ---- softmax over dist_row ----
    float sv = dist_row[t] * SCALING_F;
    float v = sv;
    #pragma unroll
    for (int m = 32; m > 0; m >>= 1) v = fmaxf(v, __shfl_xor(v, m));
    if ((t & 63) == 0) sred[t >> 6] = v;
    __syncthreads();
    float mx = sred[0];
    #pragma unroll
    for (int w8 = 1; w8 < 8; ++w8) mx = fmaxf(mx, sred[w8]);
    float e = expf(sv - mx);
    v = e;
    #pragma unroll
    for (int m = 32; m > 0; m >>= 1) v += __shfl_xor(v, m);
    if ((t & 63) == 0) sred[8 + (t >> 6)] = v;
    __syncthreads();
    float sm = 0.f;
    #pragma unroll
    for (int w8 = 0; w8 < 8; ++w8) sm += sred[8 + w8];
    float p = e / sm;

    // ---- pfe1 via linearity: pfe1[k] = pw[k] . (sum_j p[j]*pos[j]) ----
    float px = pos[(b * 512 + t) * 3 + 0];
    float py = pos[(b * 512 + t) * 3 + 1];
    float pz = pos[(b * 512 + t) * 3 + 2];
    float vx = p * px, vy = p * py, vz = p * pz;
    #pragma unroll
    for (int m = 32; m > 0; m >>= 1) {
        vx += __shfl_xor(vx, m); vy += __shfl_xor(vy, m); vz += __shfl_xor(vz, m);
    }
    __syncthreads();      // rb re-use after efsum reads done
    if ((t & 63) == 0) {
        int w8 = t >> 6;
        rb[w8] = vx; rb[8 + w8] = vy; rb[16 + w8] = vz;
    }
    __syncthreads();
    if (t < 128) {
        float w0 = 0.f, w1v = 0.f, w2v = 0.f;
        #pragma unroll
        for (int w8 = 0; w8 < 8; ++w8) {
            w0 += rb[w8]; w1v += rb[8 + w8]; w2v += rb[16 + w8];
        }
        pfe1[(size_t)row * 128 + t] = pw[t * 3 + 0] * w0 + pw[t * 3 + 1] * w1v + pw[t * 3 + 2] * w2v;
    }
}

// ---------------- final projection: tiled f32 GEMM ----------------
__global__ __launch_bounds__(256) void pfe_kernel(
    const float* __restrict__ pfe1,
    const float* __restrict__ efsum,
    const float* __restrict__ wfet,   // [K=128][D=1024]
    const float* __restrict__ wpt,    // [K=128][D=1024]
    const float* __restrict__ pb,
    const unsigned char* __restrict__ padm,
    float* __restrict__ out)
{
    __shared__ __align__(16) float As[2 * 32 * 132];
    __shared__ __align__(16) float Bs[2 * 16 * 128];
    const int t  = threadIdx.x;
    const int tx = t & 31;
    const int ty = t >> 5;
    const int r0 = (blockIdx.x >> 3) * 32;
    const int d0 = (blockIdx.x & 7) * 128;

    #pragma unroll
    for (int q = 0; q < 16; ++q) {
        int ii = t + q * 256;
        int r = ii >> 7, k = ii & 127;
        As[(0 * 32 + r) * 132 + k] = pfe1 [(size_t)(r0 + r) * 128 + k];
        As[(1 * 32 + r) * 132 + k] = efsum[(size_t)(r0 + r) * 128 + k];
    }

    f32x4 acc[4];
    #pragma unroll
    for (int rr = 0; rr < 4; ++rr) acc[rr] = (f32x4){0.f, 0.f, 0.f, 0.f};

    for (int kc = 0; kc < 8; ++kc) {
        __syncthreads();
        #pragma unroll
        for (int q = 0; q < 2; ++q) {
            int ii = t + q * 256;
            int kr = ii >> 5, dq = ii & 31;
            f32x4 v0 = ((const f32x4*)(wfet + (size_t)(kc * 16 + kr) * 1024 + d0))[dq];
            f32x4 v1 = ((const f32x4*)(wpt  + (size_t)(kc * 16 + kr) * 1024 + d0))[dq];
            *(f32x4*)&Bs[(0 * 16 + kr) * 128 + dq * 4] = v0;
            *(f32x4*)&Bs[(1 * 16 + kr) * 128 + dq * 4] = v1;
        }
        __syncthreads();
        #pragma unroll
        for (int k4 = 0; k4 < 4; ++k4) {
            int kb = kc * 16 + k4 * 4;
            f32x4 a0[4], a1[4];
            #pragma unroll
            for (int rr = 0; rr < 4; ++rr) {
                int r = ty * 4 + rr;
                a0[rr] = *(const f32x4*)&As[(0 * 32 + r) * 132 + kb];
                a1[rr] = *(const f32x4*)&As[(1 * 32 + r) * 132 + kb];
            }
            #pragma unroll
            for (int kq = 0; kq < 4; ++kq) {
                f32x4 b0 = *(const f32x4*)&Bs[(0 * 16 + k4 * 4 + kq) * 128 + tx * 4];
                f32x4 b1 = *(const f32x4*)&Bs[(1 * 16 + k4 * 4 + kq) * 128 + tx * 4];
                #pragma unroll
                for (int rr = 0; rr < 4; ++rr) {
                    acc[rr] += a0[rr][kq] * b0 + a1[rr][kq] * b1;
                }
            }
        }
    }

    f32x4 bv = *(const f32x4*)&pb[d0 + tx * 4];
    #pragma unroll
    for (int rr = 0; rr < 4; ++rr) {
        int row = r0 + ty * 4 + rr;
        f32x4 o = acc[rr] + bv;
        if (padm[row]) o = (f32x4){0.f, 0.f, 0.f, 0.f};
        *(f32x4*)&out[(size_t)row * 1024 + d0 + tx * 4] = o;
    }
}

extern "C" void kernel_launch(void* const* d_in, const int* in_sizes, int n_in,
                              void* d_out, int out_size, void* d_ws, size_t ws_size,
                              hipStream_t stream) {
    const float* pos  = (const float*)d_in[0];
    const int*   nte  = (const int*)d_in[1];
    const unsigned char* adj  = (const unsigned char*)d_in[2];
    const unsigned char* padm = (const unsigned char*)d_in[3];
    const unsigned char* molm = (const unsigned char*)d_in[4];
    const unsigned char* clnm = (const unsigned char*)d_in[5];
    const float* pw    = (const float*)d_in[6];
    const float* wfe   = (const float*)d_in[7];
    const float* gmean = (const float*)d_in[8];
    const float* gstd  = (const float*)d_in[9];
    const float* gmul  = (const float*)d_in[10];
    const float* gbias = (const float*)d_in[11];
    const float* w1    = (const float*)d_in[12];
    const float* b1    = (const float*)d_in[13];
    const float* w2    = (const float*)d_in[14];
    const float* b2    = (const float*)d_in[15];
    const float* wp    = (const float*)d_in[16];
    const float* pb    = (const float*)d_in[17];

    float* out      = (float*)d_out;
    float* out_pfe  = out;
    float* out_gab  = out + (size_t)BB * LL * 1024;

    float* ws    = (float*)d_ws;
    float* pfe1  = ws;                  // 131072
    float* efsum = ws + 131072;         // 131072
    float* wfet  = ws + 262144;         // 131072
    float* wpt   = ws + 393216;         // 131072

    row_kernel<<<BB * LL + 128, 512, 0, stream>>>(pos, nte, adj, padm, molm, clnm,
                                                  gmean, gstd, gmul, gbias,
                                                  w1, b1, w2, b2, pw, wfe, wp,
                                                  out_gab, pfe1, efsum, wfet, wpt);
    pfe_kernel<<<256, 256, 0, stream>>>(pfe1, efsum, wfet, wpt, pb, padm, out_pfe);
}

// Round 17
// 103.521 us; speedup vs baseline: 1.7165x; 1.2373x over previous
//
#include <hip/hip_runtime.h>
#include <hip/hip_bf16.h>

typedef __attribute__((ext_vector_type(8))) short short8;
typedef __attribute__((ext_vector_type(4))) float f32x4;

static const int BB = 2;
static const int LL = 512;
#define MIN_F32 (-3.4028234663852886e+38f)
// Masked gab sentinel: must stay FINITE in bf16 (bf16(-FLT_MAX) -> -inf -> nan diff)
#define NEG_BIG (-1.0e38f)
#define SCALING_F 0.08838834764831845f
#define SQ2PI 2.5066282746310002f

// raw v_exp_f32: 2^x
__device__ __forceinline__ float exp2_hw(float x) {
    float r; asm("v_exp_f32 %0, %1" : "=v"(r) : "v"(x)); return r;
}
// Fast exact-gelu (A&S erf) -- used only to build the LUT (384 evals/block)
__device__ __forceinline__ float gelu_fast(float x) {
    float s  = x * 0.70710678118654752440f;
    float za = fabsf(s);
    float t  = __builtin_amdgcn_rcpf(fmaf(za, 0.3275911f, 1.0f));
    float p  = t * fmaf(t, fmaf(t, fmaf(t, fmaf(t, 1.061405429f, -1.453152027f),
                                        1.421413741f), -0.284496736f), 0.254829592f);
    float e  = __expf(-za * za);
    float q  = fmaf(-p, e, 1.0f);
    union { float f; unsigned u; } uq, us;
    uq.f = q; us.f = s;
    uq.u = (uq.u & 0x7FFFFFFFu) | (us.u & 0x80000000u);
    float hx = 0.5f * x;
    return fmaf(hx, uq.f, hx);
}
// packed bf16x2 via v_cvt_pk_bf16_f32 (RNE); lo -> low 16 bits
__device__ __forceinline__ unsigned pack_bf16x2(float lo, float hi) {
    __hip_bfloat162 h2 = __float22bfloat162_rn(float2{lo, hi});
    union { __hip_bfloat162 h; unsigned u; } v; v.h = h2;
    return v.u;
}
// f2bf scalar (weight staging only, once per block)
__device__ __forceinline__ unsigned short f2bf(float f) {
    union { float f; unsigned int u; } v; v.f = f;
    unsigned int u = v.u;
    return (unsigned short)((u + 0x7FFFu + ((u >> 16) & 1u)) >> 16);
}
// Row-swizzled LDS byte offset for [row][128 bf16] tiles (row stride 256B).
__device__ __forceinline__ int swz(int row, int bytecol) {
    return row * 256 + (bytecol ^ ((row & 7) << 4));
}

// ---------------- main fused row kernel: one block per (b,i), 8 waves ----------------
// R14 configuration -- the measured optimum (row 88.2us, FETCH 7MB, WRITE 67.6MB).
// Hard-won invariants (do not violate):
//  * Lockstep 3-phase tiles. Wave-private/barrier-free variants (R9-R11) amplified
//    gab HBM traffic 4-5x via drifted partial-line store bursts.
//  * P3 store pattern exactly as below (per-n 64B-contiguous lane groups, scalar
//    dwords). The dwordx4-per-lane n-major variant (R16) doubled WRITE_SIZE.
//  * VGPR budget: launch_bounds(512,4) pins the allocator at 64 VGPR; hoisting
//    W1/W2 fragments to registers (R15/R16) spills to scratch (200MB WRITE).
//  * gelu via LDS LUT + ef-gen via exp2_hw: -6.4us vs libm forms (R14 vs R13).
__global__ __launch_bounds__(512, 4) void row_kernel(
    const float* __restrict__ pos,
    const int*   __restrict__ nte,
    const unsigned char* __restrict__ adj,
    const unsigned char* __restrict__ padm,
    const unsigned char* __restrict__ molm,
    const unsigned char* __restrict__ clnm,
    const float* __restrict__ gmean,
    const float* __restrict__ gstd,
    const float* __restrict__ gmul,
    const float* __restrict__ gbias,
    const float* __restrict__ w1,
    const float* __restrict__ b1,
    const float* __restrict__ w2,
    const float* __restrict__ b2,
    const float* __restrict__ pw,
    const float* __restrict__ wfe,
    const float* __restrict__ wp,
    float* __restrict__ out_gab,
    float* __restrict__ pfe1,
    float* __restrict__ efsum,
    float* __restrict__ wfet,
    float* __restrict__ wpt)
{
    const int t = threadIdx.x;

    // ---- tail blocks: weight transpose for pfe_kernel ----
    if (blockIdx.x >= 1024) {
        int bid = blockIdx.x - 1024;          // 0..127
        #pragma unroll
        for (int q = 0; q < 4; ++q) {
            int idx = bid * 2048 + q * 512 + t;   // 0..262143
            int which = idx >> 17;
            int r = idx & 131071;                  // k*1024 + d
            int k = r >> 10;
            int d = r & 1023;
            if (which == 0) wfet[r] = wfe[d * 128 + k];
            else            wpt[r]  = wp[d * 128 + k];
        }
        return;
    }

    __shared__ __align__(16) char W1s[128 * 256];  // bf16 [jo=128][k=128], swizzled
    __shared__ __align__(16) char W2s[32 * 256];   // bf16 [n=32][jo=128], swizzled
    __shared__ __align__(16) char efs[64 * 256];   // bf16 [j=64][k=128], swizzled; scratch at end
    __shared__ __align__(16) char hs [64 * 256];   // bf16 [j=64][jo=128], swizzled
    __shared__ float dist_row[512];
    __shared__ float xval[512];
    __shared__ unsigned char flgall[512];
    __shared__ float b1s[128];
    __shared__ float b2s[32];
    __shared__ float sred[16];
    __shared__ float dsump[128];
    __shared__ float gelu_tab[384];   // gelu on [-6,6], step 1/32

    const int row = blockIdx.x;     // b*512 + i
    const int b = row >> 9;
    const int i = row & 511;

    const int w  = t >> 6;          // wave 0..7
    const int l  = t & 63;          // lane
    const int lr = l & 15;          // frag row/col index
    const int lq = l >> 4;          // frag k-group

    // ---- stage W1 + W2 as bf16, swizzled ----
    for (int idx = t; idx < 2048 + 512; idx += 512) {
        const float* src; char* dst; int r16, c16;
        if (idx < 2048) { r16 = idx >> 4;          c16 = idx & 15; src = w1 + r16 * 128 + c16 * 8; dst = W1s; }
        else            { r16 = (idx - 2048) >> 4; c16 = (idx - 2048) & 15; src = w2 + r16 * 128 + c16 * 8; dst = W2s; }
        float4 f0 = *(const float4*)(src);
        float4 f1 = *(const float4*)(src + 4);
        uint4 pk;
        pk.x = (unsigned)f2bf(f0.x) | ((unsigned)f2bf(f0.y) << 16);
        pk.y = (unsigned)f2bf(f0.z) | ((unsigned)f2bf(f0.w) << 16);
        pk.z = (unsigned)f2bf(f1.x) | ((unsigned)f2bf(f1.y) << 16);
        pk.w = (unsigned)f2bf(f1.z) | ((unsigned)f2bf(f1.w) << 16);
        *(uint4*)(dst + swz(r16, c16 * 16)) = pk;
    }
    if (t < 128) b1s[t] = b1[t];
    if (t < 32)  b2s[t] = b2[t];
    if (t < 384) gelu_tab[t] = gelu_fast((t - 192) * 0.03125f);

    const bool pad_i = padm[row] != 0;
    const bool force_adj = (clnm[row] != 0) || (molm[row] == 0);
    const float pix = pos[row * 3 + 0], piy = pos[row * 3 + 1], piz = pos[row * 3 + 2];

    // ---- per-j scalars for ALL 512 j, fully parallel (1 j / thread) ----
    {
        int2 e2 = ((const int2*)nte)[row * 512 + t];
        float mul = gmul[e2.x] + gmul[e2.y];
        float bia = gbias[e2.x] + gbias[e2.y];
        float dx = pix - pos[(b * 512 + t) * 3 + 0];
        float dy = piy - pos[(b * 512 + t) * 3 + 1];
        float dz = piz - pos[(b * 512 + t) * 3 + 2];
        float dist = sqrtf(dx * dx + dy * dy + dz * dz + 1e-12f);
        xval[t] = mul * dist + bia;
        int padj = padm[b * 512 + t] ? 1 : 0;
        int adje = (force_adj || adj[row * 512 + t]) ? 2 : 0;
        flgall[t] = (unsigned char)(padj | adje);
    }

    // ---- per-thread gaussian params: 8 consecutive k, exp2-folded ----
    const int k0 = (t & 15) * 8;
    const int js = t >> 4;          // j-slot 0..31
    float mean_q[8], istd_q[8], lnc_q[8], efacc[8];
    #pragma unroll
    for (int q = 0; q < 8; ++q) {
        float gsv = fabsf(gstd[k0 + q]) + 1e-5f;
        mean_q[q] = gmean[k0 + q];
        istd_q[q] = 0.84932180f / gsv;              // sqrt(0.5*log2(e))/sigma
        lnc_q[q]  = -log2f(SQ2PI * gsv);
        efacc[q]  = 0.f;
    }

    // gelu via LUT: clamp -> interp; exactness only needed to bf16
    auto gelu_lut = [&](float x) -> float {
        float xc = fminf(fmaxf(x, -6.0f), 6.0f);
        float f  = fminf(fmaf(xc, 32.0f, 192.0f), 382.99f);
        float ff = floorf(f);
        float fr = f - ff;
        int idx = (int)ff;
        float v0 = gelu_tab[idx];
        float v1 = gelu_tab[idx + 1];
        float r = fmaf(fr, v1 - v0, v0);
        return x > 5.9f ? x : r;
    };

    __syncthreads();

    for (int tile = 0; tile < 8; ++tile) {
        const int j0 = tile * 64;
        // P1: ef-gen, k-major packed (+ previous tile's dist combine rides here)
        if (tile > 0 && t < 64) {
            int fl = flgall[j0 - 64 + t];
            bool masked = pad_i || (fl & 1) || !(fl & 2);
            dist_row[j0 - 64 + t] = masked ? MIN_F32 : (dsump[t] + dsump[64 + t]);
        }
        #pragma unroll
        for (int jj = 0; jj < 2; ++jj) {
            int j = js + jj * 32;
            float x  = xval[j0 + j];
            float mk = (flgall[j0 + j] & 1) ? 0.0f : 1.0f;
            unsigned pk[4];
            #pragma unroll
            for (int q = 0; q < 4; ++q) {
                float a0 = (x - mean_q[2*q+0]) * istd_q[2*q+0];
                float a1 = (x - mean_q[2*q+1]) * istd_q[2*q+1];
                float e0 = exp2_hw(fmaf(a0, -a0, lnc_q[2*q+0]));
                float e1 = exp2_hw(fmaf(a1, -a1, lnc_q[2*q+1]));
                efacc[2*q+0] = fmaf(e0, mk, efacc[2*q+0]);
                efacc[2*q+1] = fmaf(e1, mk, efacc[2*q+1]);
                pk[q] = pack_bf16x2(e0, e1);
            }
            *(uint4*)(efs + swz(j, 2 * k0)) = make_uint4(pk[0], pk[1], pk[2], pk[3]);
        }
        __syncthreads();
        // P2: GEMM1 swapped  D[jo][j] = W1 @ ef^T, gelu-LUT, packed b64 stores to hs[j][jo]
        {
            const int jobase = (w & 3) * 32;     // 2 jo-tiles
            const int jbase  = (w >> 2) * 32;    // 2 j-tiles
            f32x4 a00 = {0.f,0.f,0.f,0.f}, a01 = a00, a10 = a00, a11 = a00;
            #pragma unroll
            for (int ks = 0; ks < 4; ++ks) {
                int bcol = ks * 64 + lq * 16;
                short8 av0 = *(const short8*)(W1s + swz(jobase + lr, bcol));
                short8 av1 = *(const short8*)(W1s + swz(jobase + 16 + lr, bcol));
                short8 bv0 = *(const short8*)(efs + swz(jbase + lr, bcol));
                short8 bv1 = *(const short8*)(efs + swz(jbase + 16 + lr, bcol));
                a00 = __builtin_amdgcn_mfma_f32_16x16x32_bf16(av0, bv0, a00, 0, 0, 0);
                a01 = __builtin_amdgcn_mfma_f32_16x16x32_bf16(av0, bv1, a01, 0, 0, 0);
                a10 = __builtin_amdgcn_mfma_f32_16x16x32_bf16(av1, bv0, a10, 0, 0, 0);
                a11 = __builtin_amdgcn_mfma_f32_16x16x32_bf16(av1, bv1, a11, 0, 0, 0);
            }
            #pragma unroll
            for (int mi = 0; mi < 2; ++mi) {
                int jo0 = jobase + mi * 16 + lq * 4;
                float4 bb = *(const float4*)&b1s[jo0];
                #pragma unroll
                for (int ci = 0; ci < 2; ++ci) {
                    f32x4 acc = (mi == 0) ? (ci == 0 ? a00 : a01) : (ci == 0 ? a10 : a11);
                    int j = jbase + ci * 16 + lr;
                    float g0 = gelu_lut(acc[0] + bb.x);
                    float g1 = gelu_lut(acc[1] + bb.y);
                    float g2 = gelu_lut(acc[2] + bb.z);
                    float g3 = gelu_lut(acc[3] + bb.w);
                    uint2 pv = make_uint2(pack_bf16x2(g0, g1), pack_bf16x2(g2, g3));
                    *(uint2*)(hs + swz(j, 2 * jo0)) = pv;
                }
            }
        }
        __syncthreads();
        // P3: GEMM2 transposed  C'[n][j] = W2 @ h^T  (lockstep store slab)
        {
            const int mt = w >> 2;           // n-tile (0/1)
            const int jt2 = w & 3;           // j-tile
            f32x4 acc = (f32x4){0.f, 0.f, 0.f, 0.f};
            #pragma unroll
            for (int ks = 0; ks < 4; ++ks) {
                int bcol = ks * 64 + lq * 16;
                short8 av = *(const short8*)(W2s + swz(mt * 16 + lr, bcol));
                short8 bv = *(const short8*)(hs + swz(jt2 * 16 + lr, bcol));
                acc = __builtin_amdgcn_mfma_f32_16x16x32_bf16(av, bv, acc, 0, 0, 0);
            }
            int jl = jt2 * 16 + lr;
            int jg = j0 + jl;
            int fl = flgall[jg];
            bool kill = (fl & 1) || !(fl & 2);
            float dpart = 0.f;
            size_t base = ((size_t)(b * 32 + mt * 16 + lq * 4) * 512 + i) * 512 + jg;
            #pragma unroll
            for (int r = 0; r < 4; ++r) {
                float raw = acc[r] + b2s[mt * 16 + lq * 4 + r];
                dpart += raw;
                float outv = pad_i ? 0.0f : (kill ? NEG_BIG : raw);
                out_gab[base + (size_t)r * 262144] = outv;
            }
            dpart += __shfl_xor(dpart, 16);
            dpart += __shfl_xor(dpart, 32);
            if (l < 16) dsump[mt * 64 + jl] = dpart;
        }
        __syncthreads();
    }

    // last tile's dist combine + efsum flush (efs free -> scratch)
    float* rb = (float*)efs;
    if (t < 64) {
        int fl = flgall[448 + t];
        bool masked = pad_i || (fl & 1) || !(fl & 2);
        dist_row[448 + t] = masked ? MIN_F32 : (dsump[t] + dsump[64 + t]);
    }
    // rb[js*128 + k0 + q] = efacc[q]
    *(float4*)&rb[t * 8 + 0] = make_float4(efacc[0], efacc[1], efacc[2], efacc[3]);
    *(float4*)&rb[t * 8 + 4] = make_float4(efacc[4], efacc[5], efacc[6], efacc[7]);
    __syncthreads();
    if (t < 128) {
        float s = 0.f;
        #pragma unroll
        for (int sidx = 0; sidx < 32; ++sidx) s += rb[sidx * 128 + t];
        efsum[(size_t)row * 128 + t] = s;
    }

    // ---- softmax over dist_row ----
    float sv = dist_row[t] * SCALING_F;
    float v = sv;
    #pragma unroll
    for (int m = 32; m > 0; m >>= 1) v = fmaxf(v, __shfl_xor(v, m));
    if ((t & 63) == 0) sred[t >> 6] = v;
    __syncthreads();
    float mx = sred[0];
    #pragma unroll
    for (int w8 = 1; w8 < 8; ++w8) mx = fmaxf(mx, sred[w8]);
    float e = expf(sv - mx);
    v = e;
    #pragma unroll
    for (int m = 32; m > 0; m >>= 1) v += __shfl_xor(v, m);
    if ((t & 63) == 0) sred[8 + (t >> 6)] = v;
    __syncthreads();
    float sm = 0.f;
    #pragma unroll
    for (int w8 = 0; w8 < 8; ++w8) sm += sred[8 + w8];
    float p = e / sm;

    // ---- pfe1 via linearity: pfe1[k] = pw[k] . (sum_j p[j]*pos[j]) ----
    float px = pos[(b * 512 + t) * 3 + 0];
    float py = pos[(b * 512 + t) * 3 + 1];
    float pz = pos[(b * 512 + t) * 3 + 2];
    float vx = p * px, vy = p * py, vz = p * pz;
    #pragma unroll
    for (int m = 32; m > 0; m >>= 1) {
        vx += __shfl_xor(vx, m); vy += __shfl_xor(vy, m); vz += __shfl_xor(vz, m);
    }
    __syncthreads();      // rb re-use after efsum reads done
    if ((t & 63) == 0) {
        int w8 = t >> 6;
        rb[w8] = vx; rb[8 + w8] = vy; rb[16 + w8] = vz;
    }
    __syncthreads();
    if (t < 128) {
        float w0 = 0.f, w1v = 0.f, w2v = 0.f;
        #pragma unroll
        for (int w8 = 0; w8 < 8; ++w8) {
            w0 += rb[w8]; w1v += rb[8 + w8]; w2v += rb[16 + w8];
        }
        pfe1[(size_t)row * 128 + t] = pw[t * 3 + 0] * w0 + pw[t * 3 + 1] * w1v + pw[t * 3 + 2] * w2v;
    }
}

// ---------------- final projection: tiled f32 GEMM ----------------
__global__ __launch_bounds__(256) void pfe_kernel(
    const float* __restrict__ pfe1,
    const float* __restrict__ efsum,
    const float* __restrict__ wfet,   // [K=128][D=1024]
    const float* __restrict__ wpt,    // [K=128][D=1024]
    const float* __restrict__ pb,
    const unsigned char* __restrict__ padm,
    float* __restrict__ out)
{
    __shared__ __align__(16) float As[2 * 32 * 132];
    __shared__ __align__(16) float Bs[2 * 16 * 128];
    const int t  = threadIdx.x;
    const int tx = t & 31;
    const int ty = t >> 5;
    const int r0 = (blockIdx.x >> 3) * 32;
    const int d0 = (blockIdx.x & 7) * 128;

    #pragma unroll
    for (int q = 0; q < 16; ++q) {
        int ii = t + q * 256;
        int r = ii >> 7, k = ii & 127;
        As[(0 * 32 + r) * 132 + k] = pfe1 [(size_t)(r0 + r) * 128 + k];
        As[(1 * 32 + r) * 132 + k] = efsum[(size_t)(r0 + r) * 128 + k];
    }

    f32x4 acc[4];
    #pragma unroll
    for (int rr = 0; rr < 4; ++rr) acc[rr] = (f32x4){0.f, 0.f, 0.f, 0.f};

    for (int kc = 0; kc < 8; ++kc) {
        __syncthreads();
        #pragma unroll
        for (int q = 0; q < 2; ++q) {
            int ii = t + q * 256;
            int kr = ii >> 5, dq = ii & 31;
            f32x4 v0 = ((const f32x4*)(wfet + (size_t)(kc * 16 + kr) * 1024 + d0))[dq];
            f32x4 v1 = ((const f32x4*)(wpt  + (size_t)(kc * 16 + kr) * 1024 + d0))[dq];
            *(f32x4*)&Bs[(0 * 16 + kr) * 128 + dq * 4] = v0;
            *(f32x4*)&Bs[(1 * 16 + kr) * 128 + dq * 4] = v1;
        }
        __syncthreads();
        #pragma unroll
        for (int k4 = 0; k4 < 4; ++k4) {
            int kb = kc * 16 + k4 * 4;
            f32x4 a0[4], a1[4];
            #pragma unroll
            for (int rr = 0; rr < 4; ++rr) {
                int r = ty * 4 + rr;
                a0[rr] = *(const f32x4*)&As[(0 * 32 + r) * 132 + kb];
                a1[rr] = *(const f32x4*)&As[(1 * 32 + r) * 132 + kb];
            }
            #pragma unroll
            for (int kq = 0; kq < 4; ++kq) {
                f32x4 b0 = *(const f32x4*)&Bs[(0 * 16 + k4 * 4 + kq) * 128 + tx * 4];
                f32x4 b1 = *(const f32x4*)&Bs[(1 * 16 + k4 * 4 + kq) * 128 + tx * 4];
                #pragma unroll
                for (int rr = 0; rr < 4; ++rr) {
                    acc[rr] += a0[rr][kq] * b0 + a1[rr][kq] * b1;
                }
            }
        }
    }

    f32x4 bv = *(const f32x4*)&pb[d0 + tx * 4];
    #pragma unroll
    for (int rr = 0; rr < 4; ++rr) {
        int row = r0 + ty * 4 + rr;
        f32x4 o = acc[rr] + bv;
        if (padm[row]) o = (f32x4){0.f, 0.f, 0.f, 0.f};
        *(f32x4*)&out[(size_t)row * 1024 + d0 + tx * 4] = o;
    }
}

extern "C" void kernel_launch(void* const* d_in, const int* in_sizes, int n_in,
                              void* d_out, int out_size, void* d_ws, size_t ws_size,
                              hipStream_t stream) {
    const float* pos  = (const float*)d_in[0];
    const int*   nte  = (const int*)d_in[1];
    const unsigned char* adj  = (const unsigned char*)d_in[2];
    const unsigned char* padm = (const unsigned char*)d_in[3];
    const unsigned char* molm = (const unsigned char*)d_in[4];
    const unsigned char* clnm = (const unsigned char*)d_in[5];
    const float* pw    = (const float*)d_in[6];
    const float* wfe   = (const float*)d_in[7];
    const float* gmean = (const float*)d_in[8];
    const float* gstd  = (const float*)d_in[9];
    const float* gmul  = (const float*)d_in[10];
    const float* gbias = (const float*)d_in[11];
    const float* w1    = (const float*)d_in[12];
    const float* b1    = (const float*)d_in[13];
    const float* w2    = (const float*)d_in[14];
    const float* b2    = (const float*)d_in[15];
    const float* wp    = (const float*)d_in[16];
    const float* pb    = (const float*)d_in[17];

    float* out      = (float*)d_out;
    float* out_pfe  = out;
    float* out_gab  = out + (size_t)BB * LL * 1024;

    float* ws    = (float*)d_ws;
    float* pfe1  = ws;                  // 131072
    float* efsum = ws + 131072;         // 131072
    float* wfet  = ws + 262144;         // 131072
    float* wpt   = ws + 393216;         // 131072

    row_kernel<<<BB * LL + 128, 512, 0, stream>>>(pos, nte, adj, padm, molm, clnm,
                                                  gmean, gstd, gmul, gbias,
                                                  w1, b1, w2, b2, pw, wfe, wp,
                                                  out_gab, pfe1, efsum, wfet, wpt);
    pfe_kernel<<<256, 256, 0, stream>>>(pfe1, efsum, wfet, wpt, pb, padm, out_pfe);
}

// Round 18
// 102.097 us; speedup vs baseline: 1.7405x; 1.0139x over previous
//
#include <hip/hip_runtime.h>
#include <hip/hip_bf16.h>

typedef __attribute__((ext_vector_type(8))) short short8;
typedef __attribute__((ext_vector_type(4))) float f32x4;

static const int BB = 2;
static const int LL = 512;
#define MIN_F32 (-3.4028234663852886e+38f)
// Masked gab sentinel: must stay FINITE in bf16 (bf16(-FLT_MAX) -> -inf -> nan diff)
#define NEG_BIG (-1.0e38f)
#define SCALING_F 0.08838834764831845f
#define SQ2PI 2.5066282746310002f

// raw v_exp_f32: 2^x
__device__ __forceinline__ float exp2_hw(float x) {
    float r; asm("v_exp_f32 %0, %1" : "=v"(r) : "v"(x)); return r;
}
// Fast exact-gelu (A&S erf) -- used only to build the LUT (384 evals/block)
__device__ __forceinline__ float gelu_fast(float x) {
    float s  = x * 0.70710678118654752440f;
    float za = fabsf(s);
    float t  = __builtin_amdgcn_rcpf(fmaf(za, 0.3275911f, 1.0f));
    float p  = t * fmaf(t, fmaf(t, fmaf(t, fmaf(t, 1.061405429f, -1.453152027f),
                                        1.421413741f), -0.284496736f), 0.254829592f);
    float e  = __expf(-za * za);
    float q  = fmaf(-p, e, 1.0f);
    union { float f; unsigned u; } uq, us;
    uq.f = q; us.f = s;
    uq.u = (uq.u & 0x7FFFFFFFu) | (us.u & 0x80000000u);
    float hx = 0.5f * x;
    return fmaf(hx, uq.f, hx);
}
// packed bf16x2 via v_cvt_pk_bf16_f32 (RNE); lo -> low 16 bits
__device__ __forceinline__ unsigned pack_bf16x2(float lo, float hi) {
    __hip_bfloat162 h2 = __float22bfloat162_rn(float2{lo, hi});
    union { __hip_bfloat162 h; unsigned u; } v; v.h = h2;
    return v.u;
}
// f2bf scalar (weight staging only, once per block)
__device__ __forceinline__ unsigned short f2bf(float f) {
    union { float f; unsigned int u; } v; v.f = f;
    unsigned int u = v.u;
    return (unsigned short)((u + 0x7FFFu + ((u >> 16) & 1u)) >> 16);
}
// Row-swizzled LDS byte offset for [row][128 bf16] tiles (row stride 256B).
__device__ __forceinline__ int swz(int row, int bytecol) {
    return row * 256 + (bytecol ^ ((row & 7) << 4));
}

// ---------------- main fused row kernel: one block per (b,i), 8 waves ----------------
// R14 configuration + R18 phase merge. Hard-won invariants (do not violate):
//  * Lockstep phase tiles: wave-private/barrier-free variants (R9-R11) amplified
//    gab HBM traffic 4-5x via drifted partial-line store bursts.
//  * P3 store pattern exactly as below (per-n 64B-contiguous lane groups).
//  * launch_bounds(512,4) pins allocator at 64 VGPR; hoisting W1/W2 frags spills.
//  * gelu via LDS LUT + ef-gen via exp2_hw (R14: -6.4us vs libm).
// R18: P3(t) and ef-gen(t+1) touch disjoint LDS buffers (hs vs efs) -> merged into
// one phase. Barriers 24->17; exp2 VALU overlaps MFMA+store latency.
__global__ __launch_bounds__(512, 4) void row_kernel(
    const float* __restrict__ pos,
    const int*   __restrict__ nte,
    const unsigned char* __restrict__ adj,
    const unsigned char* __restrict__ padm,
    const unsigned char* __restrict__ molm,
    const unsigned char* __restrict__ clnm,
    const float* __restrict__ gmean,
    const float* __restrict__ gstd,
    const float* __restrict__ gmul,
    const float* __restrict__ gbias,
    const float* __restrict__ w1,
    const float* __restrict__ b1,
    const float* __restrict__ w2,
    const float* __restrict__ b2,
    const float* __restrict__ pw,
    const float* __restrict__ wfe,
    const float* __restrict__ wp,
    float* __restrict__ out_gab,
    float* __restrict__ pfe1,
    float* __restrict__ efsum,
    float* __restrict__ wfet,
    float* __restrict__ wpt)
{
    const int t = threadIdx.x;

    // ---- tail blocks: weight transpose for pfe_kernel ----
    if (blockIdx.x >= 1024) {
        int bid = blockIdx.x - 1024;          // 0..127
        #pragma unroll
        for (int q = 0; q < 4; ++q) {
            int idx = bid * 2048 + q * 512 + t;   // 0..262143
            int which = idx >> 17;
            int r = idx & 131071;                  // k*1024 + d
            int k = r >> 10;
            int d = r & 1023;
            if (which == 0) wfet[r] = wfe[d * 128 + k];
            else            wpt[r]  = wp[d * 128 + k];
        }
        return;
    }

    __shared__ __align__(16) char W1s[128 * 256];  // bf16 [jo=128][k=128], swizzled
    __shared__ __align__(16) char W2s[32 * 256];   // bf16 [n=32][jo=128], swizzled
    __shared__ __align__(16) char efs[64 * 256];   // bf16 [j=64][k=128], swizzled; scratch at end
    __shared__ __align__(16) char hs [64 * 256];   // bf16 [j=64][jo=128], swizzled
    __shared__ float dist_row[512];
    __shared__ float xval[512];
    __shared__ unsigned char flgall[512];
    __shared__ float b1s[128];
    __shared__ float b2s[32];
    __shared__ float sred[16];
    __shared__ float dsump[128];
    __shared__ float gelu_tab[384];   // gelu on [-6,6], step 1/32

    const int row = blockIdx.x;     // b*512 + i
    const int b = row >> 9;
    const int i = row & 511;

    const int w  = t >> 6;          // wave 0..7
    const int l  = t & 63;          // lane
    const int lr = l & 15;          // frag row/col index
    const int lq = l >> 4;          // frag k-group

    // ---- stage W1 + W2 as bf16, swizzled ----
    for (int idx = t; idx < 2048 + 512; idx += 512) {
        const float* src; char* dst; int r16, c16;
        if (idx < 2048) { r16 = idx >> 4;          c16 = idx & 15; src = w1 + r16 * 128 + c16 * 8; dst = W1s; }
        else            { r16 = (idx - 2048) >> 4; c16 = (idx - 2048) & 15; src = w2 + r16 * 128 + c16 * 8; dst = W2s; }
        float4 f0 = *(const float4*)(src);
        float4 f1 = *(const float4*)(src + 4);
        uint4 pk;
        pk.x = (unsigned)f2bf(f0.x) | ((unsigned)f2bf(f0.y) << 16);
        pk.y = (unsigned)f2bf(f0.z) | ((unsigned)f2bf(f0.w) << 16);
        pk.z = (unsigned)f2bf(f1.x) | ((unsigned)f2bf(f1.y) << 16);
        pk.w = (unsigned)f2bf(f1.z) | ((unsigned)f2bf(f1.w) << 16);
        *(uint4*)(dst + swz(r16, c16 * 16)) = pk;
    }
    if (t < 128) b1s[t] = b1[t];
    if (t < 32)  b2s[t] = b2[t];
    if (t < 384) gelu_tab[t] = gelu_fast((t - 192) * 0.03125f);

    const bool pad_i = padm[row] != 0;
    const bool force_adj = (clnm[row] != 0) || (molm[row] == 0);
    const float pix = pos[row * 3 + 0], piy = pos[row * 3 + 1], piz = pos[row * 3 + 2];

    // ---- per-j scalars for ALL 512 j, fully parallel (1 j / thread) ----
    {
        int2 e2 = ((const int2*)nte)[row * 512 + t];
        float mul = gmul[e2.x] + gmul[e2.y];
        float bia = gbias[e2.x] + gbias[e2.y];
        float dx = pix - pos[(b * 512 + t) * 3 + 0];
        float dy = piy - pos[(b * 512 + t) * 3 + 1];
        float dz = piz - pos[(b * 512 + t) * 3 + 2];
        float dist = sqrtf(dx * dx + dy * dy + dz * dz + 1e-12f);
        xval[t] = mul * dist + bia;
        int padj = padm[b * 512 + t] ? 1 : 0;
        int adje = (force_adj || adj[row * 512 + t]) ? 2 : 0;
        flgall[t] = (unsigned char)(padj | adje);
    }

    // ---- per-thread gaussian params: 8 consecutive k, exp2-folded ----
    const int k0 = (t & 15) * 8;
    const int js = t >> 4;          // j-slot 0..31
    float mean_q[8], istd_q[8], lnc_q[8], efacc[8];
    #pragma unroll
    for (int q = 0; q < 8; ++q) {
        float gsv = fabsf(gstd[k0 + q]) + 1e-5f;
        mean_q[q] = gmean[k0 + q];
        istd_q[q] = 0.84932180f / gsv;              // sqrt(0.5*log2(e))/sigma
        lnc_q[q]  = -log2f(SQ2PI * gsv);
        efacc[q]  = 0.f;
    }

    // gelu via LUT: clamp -> interp; exactness only needed to bf16
    auto gelu_lut = [&](float x) -> float {
        float xc = fminf(fmaxf(x, -6.0f), 6.0f);
        float f  = fminf(fmaf(xc, 32.0f, 192.0f), 382.99f);
        float ff = floorf(f);
        float fr = f - ff;
        int idx = (int)ff;
        float v0 = gelu_tab[idx];
        float v1 = gelu_tab[idx + 1];
        float r = fmaf(fr, v1 - v0, v0);
        return x > 5.9f ? x : r;
    };

    // ef-gen for one 64-j tile (k-major packed, b128 LDS writes)
    auto ef_gen = [&](int j0x) {
        #pragma unroll
        for (int jj = 0; jj < 2; ++jj) {
            int j = js + jj * 32;
            float x  = xval[j0x + j];
            float mk = (flgall[j0x + j] & 1) ? 0.0f : 1.0f;
            unsigned pk[4];
            #pragma unroll
            for (int q = 0; q < 4; ++q) {
                float a0 = (x - mean_q[2*q+0]) * istd_q[2*q+0];
                float a1 = (x - mean_q[2*q+1]) * istd_q[2*q+1];
                float e0 = exp2_hw(fmaf(a0, -a0, lnc_q[2*q+0]));
                float e1 = exp2_hw(fmaf(a1, -a1, lnc_q[2*q+1]));
                efacc[2*q+0] = fmaf(e0, mk, efacc[2*q+0]);
                efacc[2*q+1] = fmaf(e1, mk, efacc[2*q+1]);
                pk[q] = pack_bf16x2(e0, e1);
            }
            *(uint4*)(efs + swz(j, 2 * k0)) = make_uint4(pk[0], pk[1], pk[2], pk[3]);
        }
    };

    __syncthreads();          // staging + xval/flgall visible
    ef_gen(0);                // prologue: tile 0 edge features
    __syncthreads();

    for (int tile = 0; tile < 8; ++tile) {
        const int j0 = tile * 64;
        // Phase A: GEMM1 (+ previous tile's dist combine rides here)
        if (tile > 0 && t < 64) {
            int fl = flgall[j0 - 64 + t];
            bool masked = pad_i || (fl & 1) || !(fl & 2);
            dist_row[j0 - 64 + t] = masked ? MIN_F32 : (dsump[t] + dsump[64 + t]);
        }
        {
            const int jobase = (w & 3) * 32;     // 2 jo-tiles
            const int jbase  = (w >> 2) * 32;    // 2 j-tiles
            f32x4 a00 = {0.f,0.f,0.f,0.f}, a01 = a00, a10 = a00, a11 = a00;
            #pragma unroll
            for (int ks = 0; ks < 4; ++ks) {
                int bcol = ks * 64 + lq * 16;
                short8 av0 = *(const short8*)(W1s + swz(jobase + lr, bcol));
                short8 av1 = *(const short8*)(W1s + swz(jobase + 16 + lr, bcol));
                short8 bv0 = *(const short8*)(efs + swz(jbase + lr, bcol));
                short8 bv1 = *(const short8*)(efs + swz(jbase + 16 + lr, bcol));
                a00 = __builtin_amdgcn_mfma_f32_16x16x32_bf16(av0, bv0, a00, 0, 0, 0);
                a01 = __builtin_amdgcn_mfma_f32_16x16x32_bf16(av0, bv1, a01, 0, 0, 0);
                a10 = __builtin_amdgcn_mfma_f32_16x16x32_bf16(av1, bv0, a10, 0, 0, 0);
                a11 = __builtin_amdgcn_mfma_f32_16x16x32_bf16(av1, bv1, a11, 0, 0, 0);
            }
            #pragma unroll
            for (int mi = 0; mi < 2; ++mi) {
                int jo0 = jobase + mi * 16 + lq * 4;
                float4 bb = *(const float4*)&b1s[jo0];
                #pragma unroll
                for (int ci = 0; ci < 2; ++ci) {
                    f32x4 acc = (mi == 0) ? (ci == 0 ? a00 : a01) : (ci == 0 ? a10 : a11);
                    int j = jbase + ci * 16 + lr;
                    float g0 = gelu_lut(acc[0] + bb.x);
                    float g1 = gelu_lut(acc[1] + bb.y);
                    float g2 = gelu_lut(acc[2] + bb.z);
                    float g3 = gelu_lut(acc[3] + bb.w);
                    uint2 pv = make_uint2(pack_bf16x2(g0, g1), pack_bf16x2(g2, g3));
                    *(uint2*)(hs + swz(j, 2 * jo0)) = pv;
                }
            }
        }
        __syncthreads();
        // Phase B: GEMM2+store (reads hs) || ef-gen(t+1) (writes efs) -- disjoint LDS
        {
            const int mt = w >> 2;           // n-tile (0/1)
            const int jt2 = w & 3;           // j-tile
            f32x4 acc = (f32x4){0.f, 0.f, 0.f, 0.f};
            #pragma unroll
            for (int ks = 0; ks < 4; ++ks) {
                int bcol = ks * 64 + lq * 16;
                short8 av = *(const short8*)(W2s + swz(mt * 16 + lr, bcol));
                short8 bv = *(const short8*)(hs + swz(jt2 * 16 + lr, bcol));
                acc = __builtin_amdgcn_mfma_f32_16x16x32_bf16(av, bv, acc, 0, 0, 0);
            }
            int jl = jt2 * 16 + lr;
            int jg = j0 + jl;
            int fl = flgall[jg];
            bool kill = (fl & 1) || !(fl & 2);
            float dpart = 0.f;
            size_t base = ((size_t)(b * 32 + mt * 16 + lq * 4) * 512 + i) * 512 + jg;
            #pragma unroll
            for (int r = 0; r < 4; ++r) {
                float raw = acc[r] + b2s[mt * 16 + lq * 4 + r];
                dpart += raw;
                float outv = pad_i ? 0.0f : (kill ? NEG_BIG : raw);
                out_gab[base + (size_t)r * 262144] = outv;
            }
            dpart += __shfl_xor(dpart, 16);
            dpart += __shfl_xor(dpart, 32);
            if (l < 16) dsump[mt * 64 + jl] = dpart;
        }
        if (tile < 7) ef_gen(j0 + 64);   // exp2 VALU overlaps P3 MFMA/store drain
        __syncthreads();
    }

    // last tile's dist combine + efsum flush (efs free -> scratch)
    float* rb = (float*)efs;
    if (t < 64) {
        int fl = flgall[448 + t];
        bool masked = pad_i || (fl & 1) || !(fl & 2);
        dist_row[448 + t] = masked ? MIN_F32 : (dsump[t] + dsump[64 + t]);
    }
    // rb[js*128 + k0 + q] = efacc[q]
    *(float4*)&rb[t * 8 + 0] = make_float4(efacc[0], efacc[1], efacc[2], efacc[3]);
    *(float4*)&rb[t * 8 + 4] = make_float4(efacc[4], efacc[5], efacc[6], efacc[7]);
    __syncthreads();
    if (t < 128) {
        float s = 0.f;
        #pragma unroll
        for (int sidx = 0; sidx < 32; ++sidx) s += rb[sidx * 128 + t];
        efsum[(size_t)row * 128 + t] = s;
    }

    // ---- softmax over dist_row ----
    float sv = dist_row[t] * SCALING_F;
    float v = sv;
    #pragma unroll
    for (int m = 32; m > 0; m >>= 1) v = fmaxf(v, __shfl_xor(v, m));
    if ((t & 63) == 0) sred[t >> 6] = v;
    __syncthreads();
    float mx = sred[0];
    #pragma unroll
    for (int w8 = 1; w8 < 8; ++w8) mx = fmaxf(mx, sred[w8]);
    float e = expf(sv - mx);
    v = e;
    #pragma unroll
    for (int m = 32; m > 0; m >>= 1) v += __shfl_xor(v, m);
    if ((t & 63) == 0) sred[8 + (t >> 6)] = v;
    __syncthreads();
    float sm = 0.f;
    #pragma unroll
    for (int w8 = 0; w8 < 8; ++w8) sm += sred[8 + w8];
    float p = e / sm;

    // ---- pfe1 via linearity: pfe1[k] = pw[k] . (sum_j p[j]*pos[j]) ----
    float px = pos[(b * 512 + t) * 3 + 0];
    float py = pos[(b * 512 + t) * 3 + 1];
    float pz = pos[(b * 512 + t) * 3 + 2];
    float vx = p * px, vy = p * py, vz = p * pz;
    #pragma unroll
    for (int m = 32; m > 0; m >>= 1) {
        vx += __shfl_xor(vx, m); vy += __shfl_xor(vy, m); vz += __shfl_xor(vz, m);
    }
    __syncthreads();      // rb re-use after efsum reads done
    if ((t & 63) == 0) {
        int w8 = t >> 6;
        rb[w8] = vx; rb[8 + w8] = vy; rb[16 + w8] = vz;
    }
    __syncthreads();
    if (t < 128) {
        float w0 = 0.f, w1v = 0.f, w2v = 0.f;
        #pragma unroll
        for (int w8 = 0; w8 < 8; ++w8) {
            w0 += rb[w8]; w1v += rb[8 + w8]; w2v += rb[16 + w8];
        }
        pfe1[(size_t)row * 128 + t] = pw[t * 3 + 0] * w0 + pw[t * 3 + 1] * w1v + pw[t * 3 + 2] * w2v;
    }
}

// ---------------- final projection: tiled f32 GEMM ----------------
__global__ __launch_bounds__(256) void pfe_kernel(
    const float* __restrict__ pfe1,
    const float* __restrict__ efsum,
    const float* __restrict__ wfet,   // [K=128][D=1024]
    const float* __restrict__ wpt,    // [K=128][D=1024]
    const float* __restrict__ pb,
    const unsigned char* __restrict__ padm,
    float* __restrict__ out)
{
    __shared__ __align__(16) float As[2 * 32 * 132];
    __shared__ __align__(16) float Bs[2 * 16 * 128];
    const int t  = threadIdx.x;
    const int tx = t & 31;
    const int ty = t >> 5;
    const int r0 = (blockIdx.x >> 3) * 32;
    const int d0 = (blockIdx.x & 7) * 128;

    #pragma unroll
    for (int q = 0; q < 16; ++q) {
        int ii = t + q * 256;
        int r = ii >> 7, k = ii & 127;
        As[(0 * 32 + r) * 132 + k] = pfe1 [(size_t)(r0 + r) * 128 + k];
        As[(1 * 32 + r) * 132 + k] = efsum[(size_t)(r0 + r) * 128 + k];
    }

    f32x4 acc[4];
    #pragma unroll
    for (int rr = 0; rr < 4; ++rr) acc[rr] = (f32x4){0.f, 0.f, 0.f, 0.f};

    for (int kc = 0; kc < 8; ++kc) {
        __syncthreads();
        #pragma unroll
        for (int q = 0; q < 2; ++q) {
            int ii = t + q * 256;
            int kr = ii >> 5, dq = ii & 31;
            f32x4 v0 = ((const f32x4*)(wfet + (size_t)(kc * 16 + kr) * 1024 + d0))[dq];
            f32x4 v1 = ((const f32x4*)(wpt  + (size_t)(kc * 16 + kr) * 1024 + d0))[dq];
            *(f32x4*)&Bs[(0 * 16 + kr) * 128 + dq * 4] = v0;
            *(f32x4*)&Bs[(1 * 16 + kr) * 128 + dq * 4] = v1;
        }
        __syncthreads();
        #pragma unroll
        for (int k4 = 0; k4 < 4; ++k4) {
            int kb = kc * 16 + k4 * 4;
            f32x4 a0[4], a1[4];
            #pragma unroll
            for (int rr = 0; rr < 4; ++rr) {
                int r = ty * 4 + rr;
                a0[rr] = *(const f32x4*)&As[(0 * 32 + r) * 132 + kb];
                a1[rr] = *(const f32x4*)&As[(1 * 32 + r) * 132 + kb];
            }
            #pragma unroll
            for (int kq = 0; kq < 4; ++kq) {
                f32x4 b0 = *(const f32x4*)&Bs[(0 * 16 + k4 * 4 + kq) * 128 + tx * 4];
                f32x4 b1 = *(const f32x4*)&Bs[(1 * 16 + k4 * 4 + kq) * 128 + tx * 4];
                #pragma unroll
                for (int rr = 0; rr < 4; ++rr) {
                    acc[rr] += a0[rr][kq] * b0 + a1[rr][kq] * b1;
                }
            }
        }
    }

    f32x4 bv = *(const f32x4*)&pb[d0 + tx * 4];
    #pragma unroll
    for (int rr = 0; rr < 4; ++rr) {
        int row = r0 + ty * 4 + rr;
        f32x4 o = acc[rr] + bv;
        if (padm[row]) o = (f32x4){0.f, 0.f, 0.f, 0.f};
        *(f32x4*)&out[(size_t)row * 1024 + d0 + tx * 4] = o;
    }
}

extern "C" void kernel_launch(void* const* d_in, const int* in_sizes, int n_in,
                              void* d_out, int out_size, void* d_ws, size_t ws_size,
                              hipStream_t stream) {
    const float* pos  = (const float*)d_in[0];
    const int*   nte  = (const int*)d_in[1];
    const unsigned char* adj  = (const unsigned char*)d_in[2];
    const unsigned char* padm = (const unsigned char*)d_in[3];
    const unsigned char* molm = (const unsigned char*)d_in[4];
    const unsigned char* clnm = (const unsigned char*)d_in[5];
    const float* pw    = (const float*)d_in[6];
    const float* wfe   = (const float*)d_in[7];
    const float* gmean = (const float*)d_in[8];
    const float* gstd  = (const float*)d_in[9];
    const float* gmul  = (const float*)d_in[10];
    const float* gbias = (const float*)d_in[11];
    const float* w1    = (const float*)d_in[12];
    const float* b1    = (const float*)d_in[13];
    const float* w2    = (const float*)d_in[14];
    const float* b2    = (const float*)d_in[15];
    const float* wp    = (const float*)d_in[16];
    const float* pb    = (const float*)d_in[17];

    float* out      = (float*)d_out;
    float* out_pfe  = out;
    float* out_gab  = out + (size_t)BB * LL * 1024;

    float* ws    = (float*)d_ws;
    float* pfe1  = ws;                  // 131072
    float* efsum = ws + 131072;         // 131072
    float* wfet  = ws + 262144;         // 131072
    float* wpt   = ws + 393216;         // 131072

    row_kernel<<<BB * LL + 128, 512, 0, stream>>>(pos, nte, adj, padm, molm, clnm,
                                                  gmean, gstd, gmul, gbias,
                                                  w1, b1, w2, b2, pw, wfe, wp,
                                                  out_gab, pfe1, efsum, wfet, wpt);
    pfe_kernel<<<256, 256, 0, stream>>>(pfe1, efsum, wfet, wpt, pb, padm, out_pfe);
}